// Round 7
// baseline (451.712 us; speedup 1.0000x reference)
//
#include <hip/hip_runtime.h>
#include <hip/hip_bf16.h>
#include <math.h>
#include <stdint.h>

// SimpleSSMLayer on gfx950 — Round 16: KILL THE DFg SHUTTLE.
// R15: scan section ~175 us, of which kscanA wrote 134 MB (dt,f) fp32 that
// kscanB immediately re-read — 268 MB of HBM to avoid ~25 us of VALU.
// This round: recompute dt/f in the consumer from XIN (33.5 MB, L2-hot).
//   * kscanA2/kscanB2: 1024 blocks x 256 thr (4 waves x 64 d). Per wave:
//     dt = x[:, :32] @ Wdt^T via 16 MFMAs HELD IN REGISTERS (fp32, softplus
//     in-place). Scan thread owns one d (h[16] regs, R15 layout); per step:
//     dt fetched from MFMA regs via 4 __shfl + 3 selects (zero LDS), u from
//     rolling 4-tap conv on coalesced global reads, f = dt*u in-flight.
//     A2: forward scan from 0 -> APROD/HEND. B2: seeded scan + y + fused
//     ZG gate RMW.
//   * DFg deleted (-268 MB traffic, -134 MB ws). kscanH unchanged.
// k1/k2/kcvt/kmean byte-identical to R15 (k1 is next round's target).
// ws layout (bytes):
//   [0)          meanDv                 pad 256
//   [256)        WOB  : 1024x2048 bf16  =  4,194,304
//   [4194560)    XIN  : 8192x2048 bf16  = 33,554,432
//   [37748992)   ZG   : 8192x2048 bf16  = 33,554,432
//   [71303424)   APROD: B*P*DI*DS f32   = 16,777,216
//   [88080640)   HEND :                 = 16,777,216
//   [104857856)  HINIT:                 = 16,777,216
//   [121635072)  WDTB : 2048x32 bf16    =     131,072
//   [121766144)  XB   : 8192x1024 bf16  = 16,777,216   dead after k1
//   [138543360)  WIB  : 4096x1024 bf16  =  8,388,608   dead after k1
//   total 146,931,968 B

using bf16 = __hip_bfloat16;
typedef __attribute__((ext_vector_type(8))) __bf16 bf16x8;
typedef __attribute__((ext_vector_type(4))) float f32x4;

static constexpr int Bdim = 4;
static constexpr int Tdim = 2048;
static constexpr int DM   = 1024;
static constexpr int DI   = 2048;
static constexpr int DS   = 16;
static constexpr int DC   = 4;
static constexpr int DTR  = 32;
static constexpr int Mrows = Bdim * Tdim;   // 8192
static constexpr int P    = 32;             // scan chunks per batch
static constexpr int TC2  = Tdim / P;       // 64 steps per chunk
static constexpr float LOG2E = 1.44269504f;

__device__ __forceinline__ float b2f(bf16 v) { return __bfloat162float(v); }
__device__ __forceinline__ bf16  f2b(float v) { return __float2bfloat16(v); }
__device__ __forceinline__ float silu_f(float v) { return v / (1.0f + __expf(-v)); }
__device__ __forceinline__ float softplus_f(float v) {
  return (v > 15.0f) ? v : __logf(1.0f + __expf(v));
}
__device__ __forceinline__ float bfbits2f(unsigned short u) {
  return __uint_as_float((unsigned)u << 16);
}
__device__ __forceinline__ float exp2_f(float v) {
  return __builtin_amdgcn_exp2f(v);
}

#define GLOAD_LDS16(gp, lp)                                                  \
  __builtin_amdgcn_global_load_lds(                                          \
      (const __attribute__((address_space(1))) uint32_t*)(gp),               \
      (__attribute__((address_space(3))) uint32_t*)(lp), 16, 0, 0)

// --------------------------------------------------------------------------
__global__ __launch_bounds__(256)
void kmean(const float* __restrict__ Dv, float* __restrict__ meanp) {
  __shared__ float red[256];
  float s = 0.0f;
  for (int i = threadIdx.x; i < DI; i += 256) s += Dv[i];
  red[threadIdx.x] = s;
  __syncthreads();
  for (int o = 128; o > 0; o >>= 1) {
    if (threadIdx.x < o) red[threadIdx.x] += red[threadIdx.x + o];
    __syncthreads();
  }
  if (threadIdx.x == 0) *meanp = red[0] / (float)DI;
}

// fp32 -> bf16 bulk convert, 8 elems/thread
__device__ __forceinline__ unsigned pack2(float x, float y) {
  return (unsigned)__builtin_bit_cast(unsigned short, f2b(x)) |
         ((unsigned)__builtin_bit_cast(unsigned short, f2b(y)) << 16);
}
__global__ __launch_bounds__(256)
void kcvt(const float* __restrict__ src, bf16* __restrict__ dst, int n8) {
  const int i = blockIdx.x * 256 + threadIdx.x;
  if (i >= n8) return;
  const float4 a = reinterpret_cast<const float4*>(src)[2 * i];
  const float4 b = reinterpret_cast<const float4*>(src)[2 * i + 1];
  uint4 v;
  v.x = pack2(a.x, a.y); v.y = pack2(a.z, a.w);
  v.z = pack2(b.x, b.y); v.w = pack2(b.z, b.w);
  reinterpret_cast<uint4*>(dst)[i] = v;
}

// --------------------------------------------------------------------------
// k1: xz = x @ Wi^T + bi  (bf16 MFMA, fp32 acc). Grid (32,64).
// --------------------------------------------------------------------------
__global__ __launch_bounds__(256)
void k1(const bf16* __restrict__ A, const bf16* __restrict__ W,
        const float* __restrict__ bi,
        bf16* __restrict__ XIN, bf16* __restrict__ ZG)
{
  __shared__ bf16 Al[128 * 32];
  __shared__ bf16 Bl[128 * 32];
  const int tid  = threadIdx.x;
  const int bm   = blockIdx.y * 128;
  const int bn   = blockIdx.x * 128;
  const int lane = tid & 63, wid = tid >> 6;
  const int wr = wid >> 1, wc = wid & 1;
  const int fr = lane & 15;
  const int kg = (lane >> 4) * 8;
  const int ldr = tid >> 2, ldc = (tid & 3) * 8;
  constexpr int K = DM;

  const bf16* ga = A + (size_t)(bm + ldr) * K + ldc;
  const bf16* gb = W + (size_t)(bn + ldr) * K + ldc;

  f32x4 acc[4][4];
#pragma unroll
  for (int i = 0; i < 4; ++i)
#pragma unroll
    for (int j = 0; j < 4; ++j) acc[i][j] = (f32x4){0.f, 0.f, 0.f, 0.f};

  for (int k0 = 0; k0 < K; k0 += 32) {
    GLOAD_LDS16(ga + k0,          &Al[tid * 8]);
    GLOAD_LDS16(ga + k0 + 64 * K, &Al[2048 + tid * 8]);
    GLOAD_LDS16(gb + k0,          &Bl[tid * 8]);
    GLOAD_LDS16(gb + k0 + 64 * K, &Bl[2048 + tid * 8]);
    asm volatile("s_waitcnt vmcnt(0)" ::: "memory");
    __syncthreads();
    bf16x8 af[4], bfr[4];
#pragma unroll
    for (int i = 0; i < 4; ++i)
      af[i]  = *(const bf16x8*)&Al[(wr * 64 + i * 16 + fr) * 32 + kg];
#pragma unroll
    for (int j = 0; j < 4; ++j)
      bfr[j] = *(const bf16x8*)&Bl[(wc * 64 + j * 16 + fr) * 32 + kg];
#pragma unroll
    for (int i = 0; i < 4; ++i)
#pragma unroll
      for (int j = 0; j < 4; ++j)
        acc[i][j] = __builtin_amdgcn_mfma_f32_16x16x32_bf16(
            af[i], bfr[j], acc[i][j], 0, 0, 0);
    __syncthreads();
  }

  const int r0 = (lane >> 4) * 4;
#pragma unroll
  for (int j = 0; j < 4; ++j) {
    const int col = bn + wc * 64 + j * 16 + fr;
    const float bv = bi[col];
    const bool isx = (col < DI);           // wave-uniform (64-aligned split)
#pragma unroll
    for (int i = 0; i < 4; ++i) {
      const int rowb = bm + wr * 64 + i * 16 + r0;
#pragma unroll
      for (int r = 0; r < 4; ++r) {
        const float v = acc[i][j][r] + bv;
        if (isx) XIN[(size_t)(rowb + r) * DI + col]        = f2b(v);
        else     ZG [(size_t)(rowb + r) * DI + (col - DI)] = f2b(silu_f(v));
      }
    }
  }
}

// --------------------------------------------------------------------------
// Shared body for the register-MFMA-dt scan kernels.
// Wave layout: wave w owns d in [blockIdx.x*256 + w*64, +64). Thread owns
// d_own = that + lane. dt for (d,t) computed by 16 MFMAs; value for
// (d_own, t) lives on lane ((t&15)>>2)*16 + (lane&15), register [t>>4][jown],
// component t&3. jown = lane>>4.
// --------------------------------------------------------------------------
#define SCAN_PROLOG(NEED_C)                                                   \
  const int tid  = threadIdx.x;                                               \
  const int lane = tid & 63;                                                  \
  const int w    = tid >> 6;                                                  \
  const int dbase = blockIdx.x * 256 + w * 64;                                \
  const int d_own = dbase + lane;                                             \
  const int cg   = blockIdx.y;                                                \
  const int row0 = cg * 64;                                                   \
  const int tloc0 = row0 & (Tdim - 1);                                        \
  const int fr = lane & 15, kg = (lane >> 4) * 8;                             \
  const int jown = lane >> 4;                                                 \
  /* ---- dt via 16 register MFMAs ---- */                                    \
  bf16x8 xf[4], wf[4];                                                        \
  _Pragma("unroll")                                                           \
  for (int i = 0; i < 4; ++i)                                                 \
    xf[i] = *(const bf16x8*)&XIN[(size_t)(row0 + i * 16 + fr) * DI + kg];     \
  _Pragma("unroll")                                                           \
  for (int j = 0; j < 4; ++j)                                                 \
    wf[j] = *(const bf16x8*)&WDTB[(size_t)(dbase + j * 16 + fr) * DTR + kg];  \
  f32x4 dtv[4][4];                                                            \
  _Pragma("unroll")                                                           \
  for (int i = 0; i < 4; ++i)                                                 \
    _Pragma("unroll")                                                         \
    for (int j = 0; j < 4; ++j) {                                             \
      f32x4 z = (f32x4){0.f, 0.f, 0.f, 0.f};                                  \
      dtv[i][j] = __builtin_amdgcn_mfma_f32_16x16x32_bf16(xf[i], wf[j], z,    \
                                                          0, 0, 0);           \
    }                                                                         \
  float bj[4];                                                                \
  _Pragma("unroll")                                                           \
  for (int j = 0; j < 4; ++j) bj[j] = bdt[dbase + j * 16 + fr];               \
  _Pragma("unroll")                                                           \
  for (int i = 0; i < 4; ++i)                                                 \
    _Pragma("unroll")                                                         \
    for (int j = 0; j < 4; ++j)                                               \
      _Pragma("unroll")                                                       \
      for (int r = 0; r < 4; ++r)                                             \
        dtv[i][j][r] = softplus_f(dtv[i][j][r] + bj[j]);                      \
  /* ---- per-d constants ---- */                                             \
  float A2[DS], Bc[DS];                                                       \
  NEED_C(float Cc[DS];)                                                       \
  _Pragma("unroll")                                                           \
  for (int q = 0; q < 4; ++q) {                                               \
    const float4 al = *(const float4*)&A_log[(size_t)d_own * DS + 4 * q];     \
    const float4 bl = *(const float4*)&Bm  [(size_t)d_own * DS + 4 * q];      \
    A2[4 * q + 0] = -__expf(al.x) * LOG2E;                                    \
    A2[4 * q + 1] = -__expf(al.y) * LOG2E;                                    \
    A2[4 * q + 2] = -__expf(al.z) * LOG2E;                                    \
    A2[4 * q + 3] = -__expf(al.w) * LOG2E;                                    \
    Bc[4 * q + 0] = bl.x; Bc[4 * q + 1] = bl.y;                               \
    Bc[4 * q + 2] = bl.z; Bc[4 * q + 3] = bl.w;                               \
    NEED_C(const float4 cl = *(const float4*)&Cm[(size_t)d_own * DS + 4 * q]; \
    Cc[4 * q + 0] = cl.x; Cc[4 * q + 1] = cl.y;                               \
    Cc[4 * q + 2] = cl.z; Cc[4 * q + 3] = cl.w;)                              \
  }                                                                           \
  const float4 cwv = *(const float4*)&cw[d_own * DC];                         \
  const float w0 = cwv.x, w1 = cwv.y, w2 = cwv.z, w3 = cwv.w;                 \
  const float c0 = cb[d_own];                                                 \
  /* rolling conv window */                                                   \
  float x3 = (tloc0 >= 3) ? b2f(XIN[(size_t)(row0 - 3) * DI + d_own]) : 0.f;  \
  float x2 = (tloc0 >= 2) ? b2f(XIN[(size_t)(row0 - 2) * DI + d_own]) : 0.f;  \
  float x1 = (tloc0 >= 1) ? b2f(XIN[(size_t)(row0 - 1) * DI + d_own]) : 0.f;

#define YES(...) __VA_ARGS__
#define NO(...)

// fetch dt for step t from the register MFMA tiles (t compile-time)
#define DT_FETCH(T, OUT)                                                      \
  {                                                                           \
    const int srcl = (((T) & 15) >> 2) * 16 + fr;                             \
    const float q0 = __shfl(dtv[(T) >> 4][0][(T) & 3], srcl);                 \
    const float q1 = __shfl(dtv[(T) >> 4][1][(T) & 3], srcl);                 \
    const float q2 = __shfl(dtv[(T) >> 4][2][(T) & 3], srcl);                 \
    const float q3 = __shfl(dtv[(T) >> 4][3][(T) & 3], srcl);                 \
    OUT = (jown == 0) ? q0 : (jown == 1) ? q1 : (jown == 2) ? q2 : q3;        \
  }

// --------------------------------------------------------------------------
// kscanA2: local forward scan from 0 -> APROD (decay product) + HEND.
// Grid (DI/256, Mrows/64) = (8, 128).
// --------------------------------------------------------------------------
__global__ __launch_bounds__(256, 3)
void kscanA2(const bf16* __restrict__ XIN, const bf16* __restrict__ WDTB,
             const float* __restrict__ cw, const float* __restrict__ cb,
             const float* __restrict__ bdt,
             const float* __restrict__ A_log, const float* __restrict__ Bm,
             float* __restrict__ APROD, float* __restrict__ HEND)
{
  SCAN_PROLOG(NO)

  float h[DS];
#pragma unroll
  for (int nn = 0; nn < DS; ++nn) h[nn] = 0.0f;
  float R = 0.0f;

#pragma unroll
  for (int t = 0; t < TC2; ++t) {
    const float x0 = b2f(XIN[(size_t)(row0 + t) * DI + d_own]);
    const float cv = c0 + w0 * x3 + w1 * x2 + w2 * x1 + w3 * x0;
    const float uv = silu_f(cv);
    float dt;
    DT_FETCH(t, dt)
    const float f = dt * uv;
    R += dt;
#pragma unroll
    for (int nn = 0; nn < DS; ++nn)
      h[nn] = h[nn] * exp2_f(dt * A2[nn]) + Bc[nn] * f;
    x3 = x2; x2 = x1; x1 = x0;
  }

  float* ap = APROD + (size_t)cg * DI * DS + (size_t)d_own * DS;
  float* hp = HEND  + (size_t)cg * DI * DS + (size_t)d_own * DS;
#pragma unroll
  for (int q = 0; q < 4; ++q) {
    float4 av, hv;
    av.x = exp2_f(R * A2[4 * q + 0]); av.y = exp2_f(R * A2[4 * q + 1]);
    av.z = exp2_f(R * A2[4 * q + 2]); av.w = exp2_f(R * A2[4 * q + 3]);
    hv.x = h[4 * q + 0]; hv.y = h[4 * q + 1];
    hv.z = h[4 * q + 2]; hv.w = h[4 * q + 3];
    *(float4*)&ap[4 * q] = av;
    *(float4*)&hp[4 * q] = hv;
  }
}

// --------------------------------------------------------------------------
// kscanH: sequential combine over P=32 chunks -> per-chunk initial states.
// --------------------------------------------------------------------------
__global__ __launch_bounds__(256)
void kscanH(const float* __restrict__ APROD, const float* __restrict__ HEND,
            float* __restrict__ HINIT)
{
  const int idx = blockIdx.x * 256 + threadIdx.x;   // b*DI*DS + dn
  const int b  = idx / (DI * DS);
  const int dn = idx % (DI * DS);
  float H = 0.0f;
#pragma unroll
  for (int c = 0; c < P; ++c) {
    const size_t si = (size_t)(b * P + c) * DI * DS + dn;
    HINIT[si] = H;
    H = APROD[si] * H + HEND[si];
  }
}

// --------------------------------------------------------------------------
// kscanB2: seeded scan + y + fused gate RMW on ZG. Grid (8, 128).
// --------------------------------------------------------------------------
__global__ __launch_bounds__(256, 3)
void kscanB2(const bf16* __restrict__ XIN, bf16* __restrict__ ZG,
             const bf16* __restrict__ WDTB,
             const float* __restrict__ cw, const float* __restrict__ cb,
             const float* __restrict__ bdt,
             const float* __restrict__ A_log, const float* __restrict__ Bm,
             const float* __restrict__ Cm, const float* __restrict__ HINIT)
{
  SCAN_PROLOG(YES)

  float h[DS];
  {
    const float* ip = HINIT + (size_t)cg * DI * DS + (size_t)d_own * DS;
#pragma unroll
    for (int q = 0; q < 4; ++q) {
      const float4 iv = *(const float4*)&ip[4 * q];
      h[4 * q + 0] = iv.x; h[4 * q + 1] = iv.y;
      h[4 * q + 2] = iv.z; h[4 * q + 3] = iv.w;
    }
  }

#pragma unroll
  for (int t = 0; t < TC2; ++t) {
    const float x0 = b2f(XIN[(size_t)(row0 + t) * DI + d_own]);
    const float cv = c0 + w0 * x3 + w1 * x2 + w2 * x1 + w3 * x0;
    const float uv = silu_f(cv);
    float dt;
    DT_FETCH(t, dt)
    const float f = dt * uv;
    float y = 0.0f;
#pragma unroll
    for (int nn = 0; nn < DS; ++nn) {
      h[nn] = h[nn] * exp2_f(dt * A2[nn]) + Bc[nn] * f;
      y += h[nn] * Cc[nn];
    }
    bf16* zt = ZG + (size_t)(row0 + t) * DI + d_own;
    *zt = f2b(y * b2f(*zt));
    x3 = x2; x2 = x1; x1 = x0;
  }
}

// --------------------------------------------------------------------------
// k2: out = G @ Wo^T + bo + meanDv*x  (bf16 MFMA, fp32 acc, pure store).
// --------------------------------------------------------------------------
__global__ __launch_bounds__(256)
void k2(const bf16* __restrict__ G, const bf16* __restrict__ W,
        const float* __restrict__ x, const float* __restrict__ bo,
        const float* __restrict__ meanp, float* __restrict__ out)
{
  __shared__ bf16 Al[128 * 32];
  __shared__ bf16 Bl[128 * 32];
  const int tid  = threadIdx.x;
  const int bm   = blockIdx.y * 128;
  const int bn   = blockIdx.x * 128;
  const int lane = tid & 63, wid = tid >> 6;
  const int wr = wid >> 1, wc = wid & 1;
  const int fr = lane & 15;
  const int kg = (lane >> 4) * 8;
  const int ldr = tid >> 2, ldc = (tid & 3) * 8;
  constexpr int K = DI;

  const bf16* ga = G + (size_t)(bm + ldr) * K + ldc;
  const bf16* gb = W + (size_t)(bn + ldr) * K + ldc;
  const float mv = *meanp;

  f32x4 acc[4][4];
#pragma unroll
  for (int i = 0; i < 4; ++i)
#pragma unroll
    for (int j = 0; j < 4; ++j) acc[i][j] = (f32x4){0.f, 0.f, 0.f, 0.f};

  for (int k0 = 0; k0 < K; k0 += 32) {
    GLOAD_LDS16(ga + k0,          &Al[tid * 8]);
    GLOAD_LDS16(ga + k0 + 64 * K, &Al[2048 + tid * 8]);
    GLOAD_LDS16(gb + k0,          &Bl[tid * 8]);
    GLOAD_LDS16(gb + k0 + 64 * K, &Bl[2048 + tid * 8]);
    asm volatile("s_waitcnt vmcnt(0)" ::: "memory");
    __syncthreads();
    bf16x8 af[4], bfr[4];
#pragma unroll
    for (int i = 0; i < 4; ++i)
      af[i]  = *(const bf16x8*)&Al[(wr * 64 + i * 16 + fr) * 32 + kg];
#pragma unroll
    for (int j = 0; j < 4; ++j)
      bfr[j] = *(const bf16x8*)&Bl[(wc * 64 + j * 16 + fr) * 32 + kg];
#pragma unroll
    for (int i = 0; i < 4; ++i)
#pragma unroll
      for (int j = 0; j < 4; ++j)
        acc[i][j] = __builtin_amdgcn_mfma_f32_16x16x32_bf16(
            af[i], bfr[j], acc[i][j], 0, 0, 0);
    __syncthreads();
  }

  const int r0 = (lane >> 4) * 4;
#pragma unroll
  for (int j = 0; j < 4; ++j) {
    const int col = bn + wc * 64 + j * 16 + fr;
    const float bv = bo[col];
#pragma unroll
    for (int i = 0; i < 4; ++i) {
      const int rowb = bm + wr * 64 + i * 16 + r0;
#pragma unroll
      for (int r = 0; r < 4; ++r) {
        const size_t oi = (size_t)(rowb + r) * DM + col;
        out[oi] = acc[i][j][r] + bv + mv * x[oi];
      }
    }
  }
}

// --------------------------------------------------------------------------
extern "C" void kernel_launch(void* const* d_in, const int* in_sizes, int n_in,
                              void* d_out, int out_size, void* d_ws, size_t ws_size,
                              hipStream_t stream)
{
  const float* x    = (const float*)d_in[0];
  const float* Wi   = (const float*)d_in[1];
  const float* bi   = (const float*)d_in[2];
  const float* cw   = (const float*)d_in[3];
  const float* cb   = (const float*)d_in[4];
  const float* Wdt  = (const float*)d_in[5];
  const float* bdt  = (const float*)d_in[6];
  const float* Alog = (const float*)d_in[7];
  const float* Bm   = (const float*)d_in[8];
  const float* Cm   = (const float*)d_in[9];
  const float* Dv   = (const float*)d_in[10];
  const float* Wo   = (const float*)d_in[11];
  const float* bo   = (const float*)d_in[12];
  float* out = (float*)d_out;

  char* ws = (char*)d_ws;
  float* MEANP = (float*)(ws);
  bf16*  WOB   = (bf16*)(ws + 256);
  bf16*  XIN   = (bf16*)(ws + 4194560);
  bf16*  ZG    = (bf16*)(ws + 37748992);
  float* APROD = (float*)(ws + 71303424);
  float* HEND  = (float*)(ws + 88080640);
  float* HINIT = (float*)(ws + 104857856);
  bf16*  WDTB  = (bf16*)(ws + 121635072);
  bf16*  XB    = (bf16*)(ws + 121766144);   // dead after k1
  bf16*  WIB   = (bf16*)(ws + 138543360);   // dead after k1
  // total ws use: 146,931,968 B

  kmean<<<1, 256, 0, stream>>>(Dv, MEANP);
  kcvt<<<Mrows * DM / 8 / 256, 256, 0, stream>>>(x,  XB,  Mrows * DM / 8);
  kcvt<<<2 * DI * DM / 8 / 256, 256, 0, stream>>>(Wi, WIB, 2 * DI * DM / 8);
  kcvt<<<DM * DI / 8 / 256, 256, 0, stream>>>(Wo, WOB, DM * DI / 8);
  kcvt<<<DI * DTR / 8 / 256, 256, 0, stream>>>(Wdt, WDTB, DI * DTR / 8);

  k1<<<dim3(2 * DI / 128, Mrows / 128), 256, 0, stream>>>(XB, WIB, bi, XIN, ZG);

  kscanA2<<<dim3(DI / 256, Mrows / 64), 256, 0, stream>>>(
      XIN, WDTB, cw, cb, bdt, Alog, Bm, APROD, HEND);
  kscanH<<<dim3(Bdim * DI * DS / 256), 256, 0, stream>>>(APROD, HEND, HINIT);
  kscanB2<<<dim3(DI / 256, Mrows / 64), 256, 0, stream>>>(
      XIN, ZG, WDTB, cw, cb, bdt, Alog, Bm, Cm, HINIT);

  k2<<<dim3(DM / 128, Mrows / 128), 256, 0, stream>>>(ZG, WOB, x, bo, MEANP, out);
}